// Round 1
// baseline (2640.028 us; speedup 1.0000x reference)
//
#include <hip/hip_runtime.h>

constexpr int NS = 131072;
constexpr int D  = 128;
constexpr int K  = 512;
constexpr int FLAG_CAP = 16384;
constexpr float TAU = 0.02f;

// ws layout (bytes):
// 0:       double lossSum
// 8:       int flagCount
// 16:      float c2[K]            (2048 B)
// 2064:    float mindist[NS]      (524288 B)
// 526352:  int   labI[NS]         (524288 B)
// 1050640: int   flags[FLAG_CAP]

__global__ void k_c2(const float* __restrict__ C, float* __restrict__ c2) {
    int wave = (blockIdx.x * blockDim.x + threadIdx.x) >> 6;
    int lane = threadIdx.x & 63;
    if (wave >= K) return;
    const float* ck = C + (size_t)wave * D;
    float a = ck[lane];
    float b = ck[lane + 64];
    float s = fmaf(a, a, b * b);
    #pragma unroll
    for (int off = 32; off > 0; off >>= 1) s += __shfl_xor(s, off, 64);
    if (lane == 0) c2[wave] = s;
}

__global__ __launch_bounds__(256, 2) void k_main(
    const float* __restrict__ X, const float* __restrict__ C,
    const float* __restrict__ c2, float* __restrict__ labF,
    float* __restrict__ mindist, int* __restrict__ labI,
    int* __restrict__ flags, int* __restrict__ flagCount)
{
    int i = blockIdx.x * blockDim.x + threadIdx.x;
    float x[D];
    float q0 = 0.f, q1 = 0.f, q2 = 0.f, q3 = 0.f;
    const float4* xr = (const float4*)(X + (size_t)i * D);
    #pragma unroll
    for (int d = 0; d < D / 4; ++d) {
        float4 v = xr[d];
        x[4*d+0] = v.x; x[4*d+1] = v.y; x[4*d+2] = v.z; x[4*d+3] = v.w;
        q0 = fmaf(v.x, v.x, q0); q1 = fmaf(v.y, v.y, q1);
        q2 = fmaf(v.z, v.z, q2); q3 = fmaf(v.w, v.w, q3);
    }
    float x2 = (q0 + q1) + (q2 + q3);

    float min1 = 3.4e38f, min2 = 3.4e38f;
    int arg = 0;
    for (int k = 0; k < K; ++k) {
        const float* __restrict__ ck = C + (size_t)k * D;
        float a0 = 0.f, a1 = 0.f, a2 = 0.f, a3 = 0.f;
        #pragma unroll
        for (int d = 0; d < D; d += 4) {
            a0 = fmaf(x[d+0], ck[d+0], a0);
            a1 = fmaf(x[d+1], ck[d+1], a1);
            a2 = fmaf(x[d+2], ck[d+2], a2);
            a3 = fmaf(x[d+3], ck[d+3], a3);
        }
        float dot = (a0 + a1) + (a2 + a3);
        float s = fmaf(-2.0f, dot, c2[k]);   // c2[k] - 2*dot  (x2 added later; constant per row)
        bool better = s < min1;               // strict: ties keep earliest k (matches np argmin)
        min2 = better ? min1 : fminf(min2, s);
        min1 = better ? s : min1;
        arg  = better ? k : arg;
    }
    labF[i] = (float)arg;
    labI[i] = arg;
    mindist[i] = x2 + min1;
    if (min2 - min1 < TAU) {                  // ambiguous argmin -> f64 re-check
        int p = atomicAdd(flagCount, 1);
        if (p < FLAG_CAP) flags[p] = i;
    }
}

__global__ void k_refine(const float* __restrict__ X, const float* __restrict__ C,
                         const int* __restrict__ flagCount, const int* __restrict__ flags,
                         float* __restrict__ labF, float* __restrict__ mindist,
                         int* __restrict__ labI)
{
    int nf = *flagCount;
    if (nf > FLAG_CAP) nf = FLAG_CAP;
    int lane = threadIdx.x;  // block of 64 = 1 wave
    for (int f = blockIdx.x; f < nf; f += gridDim.x) {
        int i = flags[f];
        const float* xr = X + (size_t)i * D;
        double best = 1e300;
        int bestk = K;
        for (int k = lane; k < K; k += 64) {
            const float* ck = C + (size_t)k * D;
            double dot = 0.0, cc = 0.0;
            for (int d = 0; d < D; ++d) {
                double cd = (double)ck[d];
                dot = fma((double)xr[d], cd, dot);
                cc  = fma(cd, cd, cc);
            }
            double s = cc - 2.0 * dot;
            if (s < best) { best = s; bestk = k; }
        }
        #pragma unroll
        for (int off = 32; off > 0; off >>= 1) {
            double ob = __shfl_xor(best, off, 64);
            int okk   = __shfl_xor(bestk, off, 64);
            if (ob < best || (ob == best && okk < bestk)) { best = ob; bestk = okk; }
        }
        if (lane == 0) {
            double xx = 0.0;
            for (int d = 0; d < D; ++d) xx = fma((double)xr[d], (double)xr[d], xx);
            labF[i] = (float)bestk;
            labI[i] = bestk;
            mindist[i] = (float)(xx + best);
        }
    }
}

__global__ void k_loss(const float* __restrict__ mindist, double* __restrict__ lossSum) {
    __shared__ double sh[4];
    double s = 0.0;
    for (int i = blockIdx.x * blockDim.x + threadIdx.x; i < NS; i += gridDim.x * blockDim.x)
        s += (double)mindist[i];
    #pragma unroll
    for (int off = 32; off > 0; off >>= 1) s += __shfl_xor(s, off, 64);
    int wid = threadIdx.x >> 6, lane = threadIdx.x & 63;
    if (lane == 0) sh[wid] = s;
    __syncthreads();
    if (threadIdx.x == 0) {
        double t = (sh[0] + sh[1]) + (sh[2] + sh[3]);
        atomicAdd(lossSum, t);
    }
}

__global__ void k_centers(const float* __restrict__ X, const float* __restrict__ C,
                          const int* __restrict__ cnt, const int* __restrict__ labI,
                          float* __restrict__ outC, float* __restrict__ outCnt)
{
    int c = blockIdx.x;      // one wave per center
    int lane = threadIdx.x;  // 64
    float s0 = 0.f, s1 = 0.f;
    int m = 0;
    for (int base = 0; base < NS; base += 64) {
        int lab = labI[base + lane];
        unsigned long long mask = __ballot(lab == c);
        m += (int)__popcll(mask);
        while (mask) {
            int j = __ffsll(mask) - 1;
            mask &= mask - 1;
            const float* xr = X + (size_t)(base + j) * D;
            s0 += xr[lane];
            s1 += xr[lane + 64];
        }
    }
    int n0 = cnt[c];
    float nm = (float)(n0 + m);
    float c0 = C[(size_t)c * D + lane];
    float c1 = C[(size_t)c * D + lane + 64];
    // running mean telescopes: new = (n0*c + sum(e)) / (n0+m)
    outC[(size_t)c * D + lane]      = fmaf((float)n0, c0, s0) / nm;
    outC[(size_t)c * D + lane + 64] = fmaf((float)n0, c1, s1) / nm;
    if (lane == 0) outCnt[c] = nm;
}

__global__ void k_fin(const double* __restrict__ lossSum, float* __restrict__ outLoss) {
    outLoss[0] = (float)(*lossSum / (double)NS);
}

extern "C" void kernel_launch(void* const* d_in, const int* in_sizes, int n_in,
                              void* d_out, int out_size, void* d_ws, size_t ws_size,
                              hipStream_t stream)
{
    const float* X  = (const float*)d_in[0];
    const float* C  = (const float*)d_in[1];
    const int* cnt  = (const int*)d_in[2];

    float* out     = (float*)d_out;
    float* outLoss = out;
    float* outLab  = out + 1;
    float* outCen  = out + 1 + NS;
    float* outCnt  = out + 1 + NS + (size_t)K * D;

    char* ws = (char*)d_ws;
    double* lossSum = (double*)(ws + 0);
    int* flagCount  = (int*)(ws + 8);
    float* c2       = (float*)(ws + 16);
    float* mindist  = (float*)(ws + 16 + 2048);
    int* labI       = (int*)(ws + 16 + 2048 + (size_t)NS * 4);
    int* flags      = (int*)(ws + 16 + 2048 + (size_t)NS * 8);

    hipMemsetAsync(d_ws, 0, 16, stream);
    k_c2<<<K / 4, 256, 0, stream>>>(C, c2);
    k_main<<<NS / 256, 256, 0, stream>>>(X, C, c2, outLab, mindist, labI, flags, flagCount);
    k_refine<<<256, 64, 0, stream>>>(X, C, flagCount, flags, outLab, mindist, labI);
    k_loss<<<256, 256, 0, stream>>>(mindist, lossSum);
    k_centers<<<K, 64, 0, stream>>>(X, C, cnt, labI, outCen, outCnt);
    k_fin<<<1, 1, 0, stream>>>(lossSum, outLoss);
}

// Round 2
// 1649.422 us; speedup vs baseline: 1.6006x; 1.6006x over previous
//
#include <hip/hip_runtime.h>

constexpr int NS = 131072;
constexpr int D  = 128;
constexpr int K  = 512;
constexpr int FLAG_CAP = 32768;
constexpr float TAU = 2e-3f;

// ws layout (bytes):
// 0:       double lossSum
// 8:       int flagCount
// 16:      float c2[K]        -> 2064
// 2064:    int counts[K]      -> 4112
// 4112:    int offsets[K]     -> 6160
// 6160:    int cursor[K]      -> 8208
// 8208:    float mindist[NS]  -> 532496
// 532496:  int labI[NS]       -> 1056784
// 1056784: int flags[32768]   -> 1187856
// 1187856: int bucket[NS]     -> 1712144

__global__ void k_c2(const float* __restrict__ C, float* __restrict__ c2) {
    int wave = (blockIdx.x * blockDim.x + threadIdx.x) >> 6;
    int lane = threadIdx.x & 63;
    if (wave >= K) return;
    const float* ck = C + (size_t)wave * D;
    float a = ck[lane];
    float b = ck[lane + 64];
    float s = fmaf(a, a, b * b);
    #pragma unroll
    for (int off = 32; off > 0; off >>= 1) s += __shfl_xor(s, off, 64);
    if (lane == 0) c2[wave] = s;
}

__global__ __launch_bounds__(256, 2) void k_main(
    const float* __restrict__ X, const float* __restrict__ C,
    const float* __restrict__ c2, float* __restrict__ labF,
    float* __restrict__ mindist, int* __restrict__ labI,
    int* __restrict__ flags, int* __restrict__ flagCount)
{
    int i = blockIdx.x * blockDim.x + threadIdx.x;
    float x[D];
    float q0 = 0.f, q1 = 0.f, q2 = 0.f, q3 = 0.f;
    const float4* xr = (const float4*)(X + (size_t)i * D);
    #pragma unroll
    for (int d = 0; d < D / 4; ++d) {
        float4 v = xr[d];
        x[4*d+0] = v.x; x[4*d+1] = v.y; x[4*d+2] = v.z; x[4*d+3] = v.w;
        q0 = fmaf(v.x, v.x, q0); q1 = fmaf(v.y, v.y, q1);
        q2 = fmaf(v.z, v.z, q2); q3 = fmaf(v.w, v.w, q3);
    }
    float x2 = (q0 + q1) + (q2 + q3);

    float min1 = 3.4e38f, min2 = 3.4e38f;
    int arg = 0;
    for (int k = 0; k < K; ++k) {
        const float* __restrict__ ck = C + (size_t)k * D;
        float a0 = 0.f, a1 = 0.f, a2 = 0.f, a3 = 0.f;
        #pragma unroll
        for (int d = 0; d < D; d += 4) {
            a0 = fmaf(x[d+0], ck[d+0], a0);
            a1 = fmaf(x[d+1], ck[d+1], a1);
            a2 = fmaf(x[d+2], ck[d+2], a2);
            a3 = fmaf(x[d+3], ck[d+3], a3);
        }
        float dot = (a0 + a1) + (a2 + a3);
        float s = fmaf(-2.0f, dot, c2[k]);   // c2[k] - 2*dot (x2 is row-constant)
        bool better = s < min1;              // strict: earliest k wins ties
        min2 = better ? min1 : fminf(min2, s);
        min1 = better ? s : min1;
        arg  = better ? k : arg;
    }
    labF[i] = (float)arg;
    labI[i] = arg;
    mindist[i] = x2 + min1;
    if (min2 - min1 < TAU) {                 // ambiguous argmin -> f64 re-check
        int p = atomicAdd(flagCount, 1);
        if (p < FLAG_CAP) flags[p] = i;
    }
}

__global__ void k_refine(const float* __restrict__ X, const float* __restrict__ C,
                         const int* __restrict__ flagCount, const int* __restrict__ flags,
                         float* __restrict__ labF, float* __restrict__ mindist,
                         int* __restrict__ labI)
{
    int nf = *flagCount;
    if (nf > FLAG_CAP) nf = FLAG_CAP;
    int lane = threadIdx.x;  // block of 64 = 1 wave
    for (int f = blockIdx.x; f < nf; f += gridDim.x) {
        int i = flags[f];
        const float* xr = X + (size_t)i * D;
        double best = 1e300;
        int bestk = K;
        for (int k = lane; k < K; k += 64) {
            const float* ck = C + (size_t)k * D;
            double dot = 0.0, cc = 0.0;
            for (int d = 0; d < D; ++d) {
                double cd = (double)ck[d];
                dot = fma((double)xr[d], cd, dot);
                cc  = fma(cd, cd, cc);
            }
            double s = cc - 2.0 * dot;
            if (s < best) { best = s; bestk = k; }
        }
        #pragma unroll
        for (int off = 32; off > 0; off >>= 1) {
            double ob = __shfl_xor(best, off, 64);
            int okk   = __shfl_xor(bestk, off, 64);
            if (ob < best || (ob == best && okk < bestk)) { best = ob; bestk = okk; }
        }
        if (lane == 0) {
            double xx = 0.0;
            for (int d = 0; d < D; ++d) xx = fma((double)xr[d], (double)xr[d], xx);
            labF[i] = (float)bestk;
            labI[i] = bestk;
            mindist[i] = (float)(xx + best);
        }
    }
}

__global__ void k_loss(const float* __restrict__ mindist, double* __restrict__ lossSum) {
    __shared__ double sh[4];
    double s = 0.0;
    for (int i = blockIdx.x * blockDim.x + threadIdx.x; i < NS; i += gridDim.x * blockDim.x)
        s += (double)mindist[i];
    #pragma unroll
    for (int off = 32; off > 0; off >>= 1) s += __shfl_xor(s, off, 64);
    int wid = threadIdx.x >> 6, lane = threadIdx.x & 63;
    if (lane == 0) sh[wid] = s;
    __syncthreads();
    if (threadIdx.x == 0) {
        double t = (sh[0] + sh[1]) + (sh[2] + sh[3]);
        atomicAdd(lossSum, t);
    }
}

__global__ void k_hist(const int* __restrict__ labI, int* __restrict__ counts) {
    for (int i = blockIdx.x * blockDim.x + threadIdx.x; i < NS; i += gridDim.x * blockDim.x)
        atomicAdd(&counts[labI[i]], 1);
}

__global__ void k_scan(const int* __restrict__ counts, int* __restrict__ offsets,
                       int* __restrict__ cursor) {
    __shared__ int sh[K];
    int t = threadIdx.x;
    int my = counts[t];
    sh[t] = my;
    __syncthreads();
    for (int off = 1; off < K; off <<= 1) {
        int v = (t >= off) ? sh[t - off] : 0;
        __syncthreads();
        sh[t] += v;
        __syncthreads();
    }
    int excl = sh[t] - my;
    offsets[t] = excl;
    cursor[t] = excl;
}

__global__ void k_scatter(const int* __restrict__ labI, int* __restrict__ cursor,
                          int* __restrict__ bucket) {
    for (int i = blockIdx.x * blockDim.x + threadIdx.x; i < NS; i += gridDim.x * blockDim.x) {
        int pos = atomicAdd(&cursor[labI[i]], 1);
        bucket[pos] = i;
    }
}

__global__ __launch_bounds__(512) void k_sum(
    const float* __restrict__ X, const float* __restrict__ C,
    const int* __restrict__ cnt, const int* __restrict__ offsets,
    const int* __restrict__ counts, const int* __restrict__ bucket,
    float* __restrict__ outC, float* __restrict__ outCnt)
{
    int c = blockIdx.x;            // one block per center
    int d = threadIdx.x & 127;     // dim lane
    int p = threadIdx.x >> 7;      // sample lane 0..3
    int beg = offsets[c];
    int m   = counts[c];
    double s = 0.0;
    for (int j = beg + p; j < beg + m; j += 4) {
        int idx = bucket[j];
        s += (double)X[(size_t)idx * D + d];
    }
    __shared__ double sh[3][D];
    if (p) sh[p - 1][d] = s;
    __syncthreads();
    if (p == 0) {
        s += sh[0][d] + sh[1][d] + sh[2][d];
        int n0 = cnt[c];
        float nm = (float)(n0 + m);
        double c0 = (double)C[(size_t)c * D + d];
        outC[(size_t)c * D + d] = (float)(((double)n0 * c0 + s) / (double)nm);
        if (d == 0) outCnt[c] = nm;
    }
}

__global__ void k_fin(const double* __restrict__ lossSum, float* __restrict__ outLoss) {
    outLoss[0] = (float)(*lossSum / (double)NS);
}

extern "C" void kernel_launch(void* const* d_in, const int* in_sizes, int n_in,
                              void* d_out, int out_size, void* d_ws, size_t ws_size,
                              hipStream_t stream)
{
    const float* X  = (const float*)d_in[0];
    const float* C  = (const float*)d_in[1];
    const int* cnt  = (const int*)d_in[2];

    float* out     = (float*)d_out;
    float* outLoss = out;
    float* outLab  = out + 1;
    float* outCen  = out + 1 + NS;
    float* outCnt  = out + 1 + NS + (size_t)K * D;

    char* ws = (char*)d_ws;
    double* lossSum = (double*)(ws + 0);
    int* flagCount  = (int*)(ws + 8);
    float* c2       = (float*)(ws + 16);
    int* counts     = (int*)(ws + 2064);
    int* offsets    = (int*)(ws + 4112);
    int* cursor     = (int*)(ws + 6160);
    float* mindist  = (float*)(ws + 8208);
    int* labI       = (int*)(ws + 532496);
    int* flags      = (int*)(ws + 1056784);
    int* bucket     = (int*)(ws + 1187856);

    hipMemsetAsync(d_ws, 0, 4112, stream);   // lossSum, flagCount, c2, counts
    k_c2<<<K / 4, 256, 0, stream>>>(C, c2);
    k_main<<<NS / 256, 256, 0, stream>>>(X, C, c2, outLab, mindist, labI, flags, flagCount);
    k_refine<<<1024, 64, 0, stream>>>(X, C, flagCount, flags, outLab, mindist, labI);
    k_loss<<<256, 256, 0, stream>>>(mindist, lossSum);
    k_hist<<<512, 256, 0, stream>>>(labI, counts);
    k_scan<<<1, K, 0, stream>>>(counts, offsets, cursor);
    k_scatter<<<512, 256, 0, stream>>>(labI, cursor, bucket);
    k_sum<<<K, 512, 0, stream>>>(X, C, cnt, offsets, counts, bucket, outCen, outCnt);
    k_fin<<<1, 1, 0, stream>>>(lossSum, outLoss);
}

// Round 3
// 871.785 us; speedup vs baseline: 3.0283x; 1.8920x over previous
//
#include <hip/hip_runtime.h>

constexpr int NS = 131072;
constexpr int D  = 128;
constexpr int K  = 512;
constexpr int FLAG_CAP = 32768;
constexpr float TAU = 2e-3f;
constexpr int SEG = 64;
constexpr float FIXSCALE = 1048576.0f;       // 2^20
constexpr double INVFIX  = 1.0 / 1048576.0;

// ws layout (bytes):
// 0:       double lossSum
// 8:       int flagCount
// 16:      float c2[K]        -> 2064
// 2064:    int counts[K]      -> 4112
// 4112:    int offsets[K]     -> 6160
// 6160:    int cursor[K]      -> 8208
// 8208:    float mindist[NS]  -> 532496
// 532496:  int labI[NS]       -> 1056784
// 1056784: int flags[32768]   -> 1187856
// 1187856: int bucket[NS]     -> 1712144
// 1712144: u64 acc[K*D]       -> 2236432

__global__ void k_c2(const float* __restrict__ C, float* __restrict__ c2) {
    int wave = (blockIdx.x * blockDim.x + threadIdx.x) >> 6;
    int lane = threadIdx.x & 63;
    if (wave >= K) return;
    const float* ck = C + (size_t)wave * D;
    float a = ck[lane];
    float b = ck[lane + 64];
    float s = fmaf(a, a, b * b);
    #pragma unroll
    for (int off = 32; off > 0; off >>= 1) s += __shfl_xor(s, off, 64);
    if (lane == 0) c2[wave] = s;
}

__global__ __launch_bounds__(256, 2) void k_main(
    const float* __restrict__ X, const float* __restrict__ C,
    const float* __restrict__ c2, float* __restrict__ labF,
    float* __restrict__ mindist, int* __restrict__ labI,
    int* __restrict__ flags, int* __restrict__ flagCount)
{
    int i = blockIdx.x * blockDim.x + threadIdx.x;
    float x[D];
    float q0 = 0.f, q1 = 0.f, q2 = 0.f, q3 = 0.f;
    const float4* xr = (const float4*)(X + (size_t)i * D);
    #pragma unroll
    for (int d = 0; d < D / 4; ++d) {
        float4 v = xr[d];
        x[4*d+0] = v.x; x[4*d+1] = v.y; x[4*d+2] = v.z; x[4*d+3] = v.w;
        q0 = fmaf(v.x, v.x, q0); q1 = fmaf(v.y, v.y, q1);
        q2 = fmaf(v.z, v.z, q2); q3 = fmaf(v.w, v.w, q3);
    }
    float x2 = (q0 + q1) + (q2 + q3);

    float min1 = 3.4e38f, min2 = 3.4e38f;
    int arg = 0;
    for (int k = 0; k < K; ++k) {
        const float* __restrict__ ck = C + (size_t)k * D;
        float a0 = 0.f, a1 = 0.f, a2 = 0.f, a3 = 0.f;
        #pragma unroll
        for (int d = 0; d < D; d += 4) {
            a0 = fmaf(x[d+0], ck[d+0], a0);
            a1 = fmaf(x[d+1], ck[d+1], a1);
            a2 = fmaf(x[d+2], ck[d+2], a2);
            a3 = fmaf(x[d+3], ck[d+3], a3);
        }
        float dot = (a0 + a1) + (a2 + a3);
        float s = fmaf(-2.0f, dot, c2[k]);   // c2[k] - 2*dot (x2 is row-constant)
        bool better = s < min1;              // strict: earliest k wins ties
        min2 = better ? min1 : fminf(min2, s);
        min1 = better ? s : min1;
        arg  = better ? k : arg;
    }
    labF[i] = (float)arg;
    labI[i] = arg;
    mindist[i] = x2 + min1;
    if (min2 - min1 < TAU) {                 // ambiguous argmin -> f64 re-check
        int p = atomicAdd(flagCount, 1);
        if (p < FLAG_CAP) flags[p] = i;
    }
}

__global__ void k_refine(const float* __restrict__ X, const float* __restrict__ C,
                         const int* __restrict__ flagCount, const int* __restrict__ flags,
                         float* __restrict__ labF, float* __restrict__ mindist,
                         int* __restrict__ labI)
{
    int nf = *flagCount;
    if (nf > FLAG_CAP) nf = FLAG_CAP;
    int lane = threadIdx.x;  // block of 64 = 1 wave
    for (int f = blockIdx.x; f < nf; f += gridDim.x) {
        int i = flags[f];
        const float* xr = X + (size_t)i * D;
        double best = 1e300;
        int bestk = K;
        for (int k = lane; k < K; k += 64) {
            const float* ck = C + (size_t)k * D;
            double dot = 0.0, cc = 0.0;
            for (int d = 0; d < D; ++d) {
                double cd = (double)ck[d];
                dot = fma((double)xr[d], cd, dot);
                cc  = fma(cd, cd, cc);
            }
            double s = cc - 2.0 * dot;
            if (s < best) { best = s; bestk = k; }
        }
        #pragma unroll
        for (int off = 32; off > 0; off >>= 1) {
            double ob = __shfl_xor(best, off, 64);
            int okk   = __shfl_xor(bestk, off, 64);
            if (ob < best || (ob == best && okk < bestk)) { best = ob; bestk = okk; }
        }
        if (lane == 0) {
            double xx = 0.0;
            for (int d = 0; d < D; ++d) xx = fma((double)xr[d], (double)xr[d], xx);
            labF[i] = (float)bestk;
            labI[i] = bestk;
            mindist[i] = (float)(xx + best);
        }
    }
}

__global__ void k_loss(const float* __restrict__ mindist, double* __restrict__ lossSum) {
    __shared__ double sh[4];
    double s = 0.0;
    for (int i = blockIdx.x * blockDim.x + threadIdx.x; i < NS; i += gridDim.x * blockDim.x)
        s += (double)mindist[i];
    #pragma unroll
    for (int off = 32; off > 0; off >>= 1) s += __shfl_xor(s, off, 64);
    int wid = threadIdx.x >> 6, lane = threadIdx.x & 63;
    if (lane == 0) sh[wid] = s;
    __syncthreads();
    if (threadIdx.x == 0) {
        double t = (sh[0] + sh[1]) + (sh[2] + sh[3]);
        atomicAdd(lossSum, t);
    }
}

__global__ void k_hist(const int* __restrict__ labI, int* __restrict__ counts) {
    for (int i = blockIdx.x * blockDim.x + threadIdx.x; i < NS; i += gridDim.x * blockDim.x)
        atomicAdd(&counts[labI[i]], 1);
}

__global__ void k_scan(const int* __restrict__ counts, int* __restrict__ offsets,
                       int* __restrict__ cursor) {
    __shared__ int sh[K];
    int t = threadIdx.x;
    int my = counts[t];
    sh[t] = my;
    __syncthreads();
    for (int off = 1; off < K; off <<= 1) {
        int v = (t >= off) ? sh[t - off] : 0;
        __syncthreads();
        sh[t] += v;
        __syncthreads();
    }
    int excl = sh[t] - my;
    offsets[t] = excl;
    cursor[t] = excl;
}

__global__ void k_scatter(const int* __restrict__ labI, int* __restrict__ cursor,
                          int* __restrict__ bucket) {
    for (int i = blockIdx.x * blockDim.x + threadIdx.x; i < NS; i += gridDim.x * blockDim.x) {
        int pos = atomicAdd(&cursor[labI[i]], 1);
        bucket[pos] = i;
    }
}

// Fixed segments of the sorted bucket array; int64 fixed-point accumulation is
// exactly order-independent -> bit-deterministic despite nondeterministic
// within-bucket order from k_scatter's atomic cursor.
__global__ __launch_bounds__(128) void k_sumseg(
    const float* __restrict__ X, const int* __restrict__ labI,
    const int* __restrict__ bucket, unsigned long long* __restrict__ acc)
{
    int d = threadIdx.x;
    int beg = blockIdx.x * SEG;
    long long s = 0;
    int prev = -1;
    for (int j = beg; j < beg + SEG; ++j) {
        int idx = bucket[j];
        int lab = labI[idx];                 // uniform across the block
        if (lab != prev) {
            if (prev >= 0) atomicAdd(&acc[(size_t)prev * D + d], (unsigned long long)s);
            s = 0; prev = lab;
        }
        float v = X[(size_t)idx * D + d];
        s += (long long)__float2int_rn(v * FIXSCALE);
    }
    if (prev >= 0) atomicAdd(&acc[(size_t)prev * D + d], (unsigned long long)s);
}

__global__ void k_avg(const float* __restrict__ C, const int* __restrict__ cnt,
                      const int* __restrict__ counts,
                      const unsigned long long* __restrict__ acc,
                      float* __restrict__ outC, float* __restrict__ outCnt)
{
    int t = blockIdx.x * blockDim.x + threadIdx.x;   // over K*D
    int c = t >> 7, d = t & 127;
    double s = (double)(long long)acc[t] * INVFIX;
    int m = counts[c], n0 = cnt[c];
    double nm = (double)(n0 + m);
    outC[t] = (float)(((double)n0 * (double)C[t] + s) / nm);
    if (d == 0) outCnt[c] = (float)(n0 + m);
}

__global__ void k_fin(const double* __restrict__ lossSum, float* __restrict__ outLoss) {
    outLoss[0] = (float)(*lossSum / (double)NS);
}

extern "C" void kernel_launch(void* const* d_in, const int* in_sizes, int n_in,
                              void* d_out, int out_size, void* d_ws, size_t ws_size,
                              hipStream_t stream)
{
    const float* X  = (const float*)d_in[0];
    const float* C  = (const float*)d_in[1];
    const int* cnt  = (const int*)d_in[2];

    float* out     = (float*)d_out;
    float* outLoss = out;
    float* outLab  = out + 1;
    float* outCen  = out + 1 + NS;
    float* outCnt  = out + 1 + NS + (size_t)K * D;

    char* ws = (char*)d_ws;
    double* lossSum = (double*)(ws + 0);
    int* flagCount  = (int*)(ws + 8);
    float* c2       = (float*)(ws + 16);
    int* counts     = (int*)(ws + 2064);
    int* offsets    = (int*)(ws + 4112);
    int* cursor     = (int*)(ws + 6160);
    float* mindist  = (float*)(ws + 8208);
    int* labI       = (int*)(ws + 532496);
    int* flags      = (int*)(ws + 1056784);
    int* bucket     = (int*)(ws + 1187856);
    unsigned long long* acc = (unsigned long long*)(ws + 1712144);

    hipMemsetAsync(d_ws, 0, 4112, stream);                     // lossSum, flagCount, c2, counts
    hipMemsetAsync(ws + 1712144, 0, (size_t)K * D * 8, stream); // acc
    k_c2<<<K / 4, 256, 0, stream>>>(C, c2);
    k_main<<<NS / 256, 256, 0, stream>>>(X, C, c2, outLab, mindist, labI, flags, flagCount);
    k_refine<<<1024, 64, 0, stream>>>(X, C, flagCount, flags, outLab, mindist, labI);
    k_loss<<<256, 256, 0, stream>>>(mindist, lossSum);
    k_hist<<<512, 256, 0, stream>>>(labI, counts);
    k_scan<<<1, K, 0, stream>>>(counts, offsets, cursor);
    k_scatter<<<512, 256, 0, stream>>>(labI, cursor, bucket);
    k_sumseg<<<NS / SEG, 128, 0, stream>>>(X, labI, bucket, acc);
    k_avg<<<K * D / 256, 256, 0, stream>>>(C, cnt, counts, acc, outCen, outCnt);
    k_fin<<<1, 1, 0, stream>>>(lossSum, outLoss);
}

// Round 4
// 361.073 us; speedup vs baseline: 7.3116x; 2.4144x over previous
//
#include <hip/hip_runtime.h>

constexpr int NS = 131072;
constexpr int D  = 128;
constexpr int K  = 512;
constexpr int FLAG_CAP = 65536;
constexpr float TAU = 8e-3f;
constexpr int SEG = 32;
constexpr float FIXSCALE = 1048576.0f;       // 2^20
constexpr double INVFIX  = 1.0 / 1048576.0;

typedef __attribute__((ext_vector_type(8))) short short8;
typedef __attribute__((ext_vector_type(4))) float f32x4;

// ws layout (bytes):
// 0:       double lossSum
// 8:       int flagCount (+pad)
// 16:      float c2[K]        -> 2064
// 2064:    int counts[K]      -> 4112
// 4112:    int offsets[K]     -> 6160
// 6160:    int cursor[K]      -> 8208
// 8208:    float mindist[NS]  -> 532496
// 532496:  int labI[NS]       -> 1056784
// 1056784: int flags[65536]   -> 1318928
// 1318928: int bucket[NS]     -> 1843216
// 1843216: u64 acc[K*D]       -> 2367504
// 2367504: ushort Chi[K*D]    -> 2498576
// 2498576: ushort Clo[K*D]    -> 2629648

__device__ inline unsigned short f2bf(float f) {          // RNE f32 -> bf16 bits
    unsigned int u = __float_as_uint(f);
    unsigned int r = (u + 0x7FFFu + ((u >> 16) & 1u)) >> 16;
    return (unsigned short)r;
}
__device__ inline float bf2f(unsigned short h) {
    return __uint_as_float(((unsigned int)h) << 16);
}

__global__ void k_c2(const float* __restrict__ C, float* __restrict__ c2) {
    int wave = (blockIdx.x * blockDim.x + threadIdx.x) >> 6;
    int lane = threadIdx.x & 63;
    if (wave >= K) return;
    const float* ck = C + (size_t)wave * D;
    float a = ck[lane];
    float b = ck[lane + 64];
    float s = fmaf(a, a, b * b);
    #pragma unroll
    for (int off = 32; off > 0; off >>= 1) s += __shfl_xor(s, off, 64);
    if (lane == 0) c2[wave] = s;
}

__global__ void k_csplit(const float* __restrict__ C, unsigned short* __restrict__ Chi,
                         unsigned short* __restrict__ Clo) {
    int i = blockIdx.x * blockDim.x + threadIdx.x;   // over K*D = 65536
    float v = C[i];
    unsigned short h = f2bf(v);
    Chi[i] = h;
    Clo[i] = f2bf(v - bf2f(h));
}

// Fused split-bf16 MFMA distance + per-sample argmin.
// Swapped operands: A = centers, B = samples -> D[row=center][col=sample].
__global__ __launch_bounds__(256, 2) void k_dist(
    const float* __restrict__ X, const unsigned short* __restrict__ Chi,
    const unsigned short* __restrict__ Clo, const float* __restrict__ c2,
    float* __restrict__ labF, float* __restrict__ mindist, int* __restrict__ labI,
    int* __restrict__ flags, int* __restrict__ flagCount)
{
    __shared__ unsigned short Ah[64][136];   // X hi tile (pad 8 -> 2-way conflicts only)
    __shared__ unsigned short Al[64][136];   // X lo tile
    __shared__ float sx2[64];
    __shared__ float red1[4][64];
    __shared__ float red2[4][64];
    __shared__ int   reda[4][64];

    int tid = threadIdx.x;
    int wave = tid >> 6, lane = tid & 63;
    int l15 = lane & 15, lk = lane >> 4;
    int s0 = blockIdx.x * 64;

    // ---- stage: X f32 -> (hi,lo) bf16 LDS + per-row sumsq ----
    {
        int row = tid >> 2, part = tid & 3;
        const float4* src = (const float4*)(X + (size_t)(s0 + row) * D + part * 32);
        float q = 0.f;
        #pragma unroll
        for (int j = 0; j < 8; ++j) {
            float4 v = src[j];
            q = fmaf(v.x, v.x, fmaf(v.y, v.y, fmaf(v.z, v.z, fmaf(v.w, v.w, q))));
            ushort4 h, lo;
            h.x = f2bf(v.x); lo.x = f2bf(v.x - bf2f(h.x));
            h.y = f2bf(v.y); lo.y = f2bf(v.y - bf2f(h.y));
            h.z = f2bf(v.z); lo.z = f2bf(v.z - bf2f(h.z));
            h.w = f2bf(v.w); lo.w = f2bf(v.w - bf2f(h.w));
            *(ushort4*)&Ah[row][part * 32 + j * 4] = h;
            *(ushort4*)&Al[row][part * 32 + j * 4] = lo;
        }
        q += __shfl_xor(q, 1, 64);
        q += __shfl_xor(q, 2, 64);
        if (part == 0) sx2[row] = q;
    }
    __syncthreads();

    // ---- X fragments -> registers (shared by all chunks) ----
    short8 xh[4][4], xl[4][4];     // [sample-tile n][kstep kk]
    #pragma unroll
    for (int n = 0; n < 4; ++n)
        #pragma unroll
        for (int kk = 0; kk < 4; ++kk) {
            int r2 = n * 16 + l15, c = kk * 32 + lk * 8;
            xh[n][kk] = *(const short8*)&Ah[r2][c];
            xl[n][kk] = *(const short8*)&Al[r2][c];
        }

    float m1[4], m2[4]; int ag[4];
    #pragma unroll
    for (int n = 0; n < 4; ++n) { m1[n] = 3.4e38f; m2[n] = 3.4e38f; ag[n] = 0; }

    for (int chunk = 0; chunk < 8; ++chunk) {
        int cb = chunk * 64 + wave * 16;   // this wave's 16-center slice
        const unsigned short* pch = Chi + (size_t)(cb + l15) * D + lk * 8;
        const unsigned short* pcl = Clo + (size_t)(cb + l15) * D + lk * 8;
        short8 ah[4], al[4];
        #pragma unroll
        for (int kk = 0; kk < 4; ++kk) {
            ah[kk] = *(const short8*)(pch + kk * 32);
            al[kk] = *(const short8*)(pcl + kk * 32);
        }
        f32x4 acc[4];
        #pragma unroll
        for (int n = 0; n < 4; ++n) acc[n] = (f32x4){0.f, 0.f, 0.f, 0.f};
        #pragma unroll
        for (int kk = 0; kk < 4; ++kk) {
            #pragma unroll
            for (int n = 0; n < 4; ++n)
                acc[n] = __builtin_amdgcn_mfma_f32_16x16x32_bf16(ah[kk], xh[n][kk], acc[n], 0, 0, 0);
            #pragma unroll
            for (int n = 0; n < 4; ++n)
                acc[n] = __builtin_amdgcn_mfma_f32_16x16x32_bf16(ah[kk], xl[n][kk], acc[n], 0, 0, 0);
            #pragma unroll
            for (int n = 0; n < 4; ++n)
                acc[n] = __builtin_amdgcn_mfma_f32_16x16x32_bf16(al[kk], xh[n][kk], acc[n], 0, 0, 0);
        }
        float cc[4];
        #pragma unroll
        for (int r = 0; r < 4; ++r) cc[r] = c2[cb + lk * 4 + r];
        #pragma unroll
        for (int n = 0; n < 4; ++n)
            #pragma unroll
            for (int r = 0; r < 4; ++r) {
                float s = fmaf(-2.f, acc[n][r], cc[r]);
                int ci = cb + lk * 4 + r;
                bool b = s < m1[n];
                m2[n] = b ? m1[n] : fminf(m2[n], s);
                m1[n] = b ? s : m1[n];
                ag[n] = b ? ci : ag[n];
            }
    }

    // ---- merge across lk groups (lanes ^16, ^32 share the same sample col) ----
    #pragma unroll
    for (int off = 16; off <= 32; off <<= 1)
        #pragma unroll
        for (int n = 0; n < 4; ++n) {
            float o1 = __shfl_xor(m1[n], off, 64);
            float o2 = __shfl_xor(m2[n], off, 64);
            int   oa = __shfl_xor(ag[n], off, 64);
            bool b = (o1 < m1[n]) || (o1 == m1[n] && oa < ag[n]);
            float lo1 = b ? o1 : m1[n];
            float hi1 = b ? m1[n] : o1;
            m2[n] = fminf(fminf(m2[n], o2), hi1);
            m1[n] = lo1;
            ag[n] = b ? oa : ag[n];
        }
    if (lane < 16) {
        #pragma unroll
        for (int n = 0; n < 4; ++n) {
            red1[wave][n * 16 + l15] = m1[n];
            red2[wave][n * 16 + l15] = m2[n];
            reda[wave][n * 16 + l15] = ag[n];
        }
    }
    __syncthreads();

    // ---- cross-wave merge + output ----
    if (tid < 64) {
        float M1 = red1[0][tid], M2 = red2[0][tid]; int A = reda[0][tid];
        #pragma unroll
        for (int w = 1; w < 4; ++w) {
            float o1 = red1[w][tid], o2 = red2[w][tid]; int oa = reda[w][tid];
            bool b = (o1 < M1) || (o1 == M1 && oa < A);
            float lo1 = b ? o1 : M1;
            float hi1 = b ? M1 : o1;
            M2 = fminf(fminf(M2, o2), hi1);
            M1 = lo1;
            A = b ? oa : A;
        }
        int i = s0 + tid;
        labF[i] = (float)A;
        labI[i] = A;
        mindist[i] = sx2[tid] + M1;
        if (M2 - M1 < TAU) {
            int p = atomicAdd(flagCount, 1);
            if (p < FLAG_CAP) flags[p] = i;
        }
    }
}

__global__ void k_refine(const float* __restrict__ X, const float* __restrict__ C,
                         const int* __restrict__ flagCount, const int* __restrict__ flags,
                         float* __restrict__ labF, float* __restrict__ mindist,
                         int* __restrict__ labI)
{
    int nf = *flagCount;
    if (nf > FLAG_CAP) nf = FLAG_CAP;
    int lane = threadIdx.x;  // block of 64 = 1 wave
    for (int f = blockIdx.x; f < nf; f += gridDim.x) {
        int i = flags[f];
        const float* xr = X + (size_t)i * D;
        double best = 1e300;
        int bestk = K;
        for (int k = lane; k < K; k += 64) {
            const float* ck = C + (size_t)k * D;
            double dot = 0.0, cc = 0.0;
            for (int d = 0; d < D; ++d) {
                double cd = (double)ck[d];
                dot = fma((double)xr[d], cd, dot);
                cc  = fma(cd, cd, cc);
            }
            double s = cc - 2.0 * dot;
            if (s < best) { best = s; bestk = k; }
        }
        #pragma unroll
        for (int off = 32; off > 0; off >>= 1) {
            double ob = __shfl_xor(best, off, 64);
            int okk   = __shfl_xor(bestk, off, 64);
            if (ob < best || (ob == best && okk < bestk)) { best = ob; bestk = okk; }
        }
        if (lane == 0) {
            double xx = 0.0;
            for (int d = 0; d < D; ++d) xx = fma((double)xr[d], (double)xr[d], xx);
            labF[i] = (float)bestk;
            labI[i] = bestk;
            mindist[i] = (float)(xx + best);
        }
    }
}

__global__ void k_loss(const float* __restrict__ mindist, double* __restrict__ lossSum) {
    __shared__ double sh[4];
    double s = 0.0;
    for (int i = blockIdx.x * blockDim.x + threadIdx.x; i < NS; i += gridDim.x * blockDim.x)
        s += (double)mindist[i];
    #pragma unroll
    for (int off = 32; off > 0; off >>= 1) s += __shfl_xor(s, off, 64);
    int wid = threadIdx.x >> 6, lane = threadIdx.x & 63;
    if (lane == 0) sh[wid] = s;
    __syncthreads();
    if (threadIdx.x == 0) {
        double t = (sh[0] + sh[1]) + (sh[2] + sh[3]);
        atomicAdd(lossSum, t);
    }
}

__global__ void k_hist(const int* __restrict__ labI, int* __restrict__ counts) {
    for (int i = blockIdx.x * blockDim.x + threadIdx.x; i < NS; i += gridDim.x * blockDim.x)
        atomicAdd(&counts[labI[i]], 1);
}

__global__ void k_scan(const int* __restrict__ counts, int* __restrict__ offsets,
                       int* __restrict__ cursor) {
    __shared__ int sh[K];
    int t = threadIdx.x;
    int my = counts[t];
    sh[t] = my;
    __syncthreads();
    for (int off = 1; off < K; off <<= 1) {
        int v = (t >= off) ? sh[t - off] : 0;
        __syncthreads();
        sh[t] += v;
        __syncthreads();
    }
    int excl = sh[t] - my;
    offsets[t] = excl;
    cursor[t] = excl;
}

__global__ void k_scatter(const int* __restrict__ labI, int* __restrict__ cursor,
                          int* __restrict__ bucket) {
    for (int i = blockIdx.x * blockDim.x + threadIdx.x; i < NS; i += gridDim.x * blockDim.x) {
        int pos = atomicAdd(&cursor[labI[i]], 1);
        bucket[pos] = i;
    }
}

// Fixed segments of sorted bucket array; int64 fixed-point accumulation is
// order-independent -> bit-deterministic despite nondeterministic scatter order.
__global__ __launch_bounds__(128) void k_sumseg(
    const float* __restrict__ X, const int* __restrict__ labI,
    const int* __restrict__ bucket, unsigned long long* __restrict__ acc)
{
    int d = threadIdx.x;
    int beg = blockIdx.x * SEG;
    long long s = 0;
    int prev = -1;
    for (int j = beg; j < beg + SEG; ++j) {
        int idx = bucket[j];
        int lab = labI[idx];                 // uniform across the block
        if (lab != prev) {
            if (prev >= 0) atomicAdd(&acc[(size_t)prev * D + d], (unsigned long long)s);
            s = 0; prev = lab;
        }
        float v = X[(size_t)idx * D + d];
        s += (long long)__float2int_rn(v * FIXSCALE);
    }
    if (prev >= 0) atomicAdd(&acc[(size_t)prev * D + d], (unsigned long long)s);
}

__global__ void k_avg(const float* __restrict__ C, const int* __restrict__ cnt,
                      const int* __restrict__ counts,
                      const unsigned long long* __restrict__ acc,
                      float* __restrict__ outC, float* __restrict__ outCnt)
{
    int t = blockIdx.x * blockDim.x + threadIdx.x;   // over K*D
    int c = t >> 7, d = t & 127;
    double s = (double)(long long)acc[t] * INVFIX;
    int m = counts[c], n0 = cnt[c];
    double nm = (double)(n0 + m);
    outC[t] = (float)(((double)n0 * (double)C[t] + s) / nm);
    if (d == 0) outCnt[c] = (float)(n0 + m);
}

__global__ void k_fin(const double* __restrict__ lossSum, float* __restrict__ outLoss) {
    outLoss[0] = (float)(*lossSum / (double)NS);
}

extern "C" void kernel_launch(void* const* d_in, const int* in_sizes, int n_in,
                              void* d_out, int out_size, void* d_ws, size_t ws_size,
                              hipStream_t stream)
{
    const float* X  = (const float*)d_in[0];
    const float* C  = (const float*)d_in[1];
    const int* cnt  = (const int*)d_in[2];

    float* out     = (float*)d_out;
    float* outLoss = out;
    float* outLab  = out + 1;
    float* outCen  = out + 1 + NS;
    float* outCnt  = out + 1 + NS + (size_t)K * D;

    char* ws = (char*)d_ws;
    double* lossSum = (double*)(ws + 0);
    int* flagCount  = (int*)(ws + 8);
    float* c2       = (float*)(ws + 16);
    int* counts     = (int*)(ws + 2064);
    int* offsets    = (int*)(ws + 4112);
    int* cursor     = (int*)(ws + 6160);
    float* mindist  = (float*)(ws + 8208);
    int* labI       = (int*)(ws + 532496);
    int* flags      = (int*)(ws + 1056784);
    int* bucket     = (int*)(ws + 1318928);
    unsigned long long* acc = (unsigned long long*)(ws + 1843216);
    unsigned short* Chi = (unsigned short*)(ws + 2367504);
    unsigned short* Clo = (unsigned short*)(ws + 2498576);

    hipMemsetAsync(d_ws, 0, 4112, stream);                      // lossSum, flagCount, c2, counts
    hipMemsetAsync(ws + 1843216, 0, (size_t)K * D * 8, stream); // acc
    k_c2<<<K / 4, 256, 0, stream>>>(C, c2);
    k_csplit<<<K * D / 256, 256, 0, stream>>>(C, Chi, Clo);
    k_dist<<<NS / 64, 256, 0, stream>>>(X, Chi, Clo, c2, outLab, mindist, labI, flags, flagCount);
    k_refine<<<2048, 64, 0, stream>>>(X, C, flagCount, flags, outLab, mindist, labI);
    k_loss<<<256, 256, 0, stream>>>(mindist, lossSum);
    k_hist<<<512, 256, 0, stream>>>(labI, counts);
    k_scan<<<1, K, 0, stream>>>(counts, offsets, cursor);
    k_scatter<<<512, 256, 0, stream>>>(labI, cursor, bucket);
    k_sumseg<<<NS / SEG, 128, 0, stream>>>(X, labI, bucket, acc);
    k_avg<<<K * D / 256, 256, 0, stream>>>(C, cnt, counts, acc, outCen, outCnt);
    k_fin<<<1, 1, 0, stream>>>(lossSum, outLoss);
}

// Round 5
// 167.448 us; speedup vs baseline: 15.7663x; 2.1563x over previous
//
#include <hip/hip_runtime.h>

constexpr int NS = 131072;
constexpr int D  = 128;
constexpr int K  = 512;
constexpr int FLAG_CAP = 32768;
constexpr float TAU = 8e-3f;
constexpr int SEG = 32;
constexpr int NB = 64;            // scatter blocks
constexpr int ITEMS = NS / NB;    // 2048 items per scatter block
constexpr float FIXSCALE = 1048576.0f;       // 2^20
constexpr double INVFIX  = 1.0 / 1048576.0;

typedef __attribute__((ext_vector_type(8))) short short8;
typedef __attribute__((ext_vector_type(4))) float f32x4;

// ws layout (bytes):
// 0:       double lossSum
// 8:       int flagCount (+pad)
// 16:      float c2[K]        -> 2064
// 2064:    int counts[K]      -> 4112
// 8208:    float mindist[NS]  -> 532496
// 532496:  int labI[NS]       -> 1056784
// 1056784: int flags[32768]   -> 1187856
// 1187856: int H[NB*K]        -> 1318928
// 1318928: int bucket[NS]     -> 1843216
// 1843216: u64 acc[K*D]       -> 2367504
// 2367504: ushort Chi[K*D]    -> 2498576
// 2498576: ushort Clo[K*D]    -> 2629648

__device__ inline unsigned short f2bf(float f) {          // RNE f32 -> bf16 bits
    unsigned int u = __float_as_uint(f);
    unsigned int r = (u + 0x7FFFu + ((u >> 16) & 1u)) >> 16;
    return (unsigned short)r;
}
__device__ inline float bf2f(unsigned short h) {
    return __uint_as_float(((unsigned int)h) << 16);
}

// Fused: c2 = ||c||^2 and f32 -> (hi,lo) bf16 split. One wave per center.
__global__ void k_prep(const float* __restrict__ C, float* __restrict__ c2,
                       unsigned short* __restrict__ Chi, unsigned short* __restrict__ Clo) {
    int wave = (blockIdx.x * blockDim.x + threadIdx.x) >> 6;
    int lane = threadIdx.x & 63;
    const float* ck = C + (size_t)wave * D;
    float a = ck[lane];
    float b = ck[lane + 64];
    unsigned short ha = f2bf(a), hb = f2bf(b);
    size_t o = (size_t)wave * D + lane;
    Chi[o] = ha;           Clo[o] = f2bf(a - bf2f(ha));
    Chi[o + 64] = hb;      Clo[o + 64] = f2bf(b - bf2f(hb));
    float s = fmaf(a, a, b * b);
    #pragma unroll
    for (int off = 32; off > 0; off >>= 1) s += __shfl_xor(s, off, 64);
    if (lane == 0) c2[wave] = s;
}

// Fused split-bf16 MFMA distance + per-sample argmin.
// Swapped operands: A = centers, B = samples -> D[row=center][col=sample].
__global__ __launch_bounds__(256, 2) void k_dist(
    const float* __restrict__ X, const unsigned short* __restrict__ Chi,
    const unsigned short* __restrict__ Clo, const float* __restrict__ c2,
    float* __restrict__ labF, float* __restrict__ mindist, int* __restrict__ labI,
    int* __restrict__ flags, int* __restrict__ flagCount)
{
    __shared__ unsigned short Ah[64][136];   // X hi tile (pad 8 -> 2-way conflicts only)
    __shared__ unsigned short Al[64][136];   // X lo tile
    __shared__ float sx2[64];
    __shared__ float red1[4][64];
    __shared__ float red2[4][64];
    __shared__ int   reda[4][64];

    int tid = threadIdx.x;
    int wave = tid >> 6, lane = tid & 63;
    int l15 = lane & 15, lk = lane >> 4;
    int s0 = blockIdx.x * 64;

    // ---- stage: X f32 -> (hi,lo) bf16 LDS + per-row sumsq ----
    {
        int row = tid >> 2, part = tid & 3;
        const float4* src = (const float4*)(X + (size_t)(s0 + row) * D + part * 32);
        float q = 0.f;
        #pragma unroll
        for (int j = 0; j < 8; ++j) {
            float4 v = src[j];
            q = fmaf(v.x, v.x, fmaf(v.y, v.y, fmaf(v.z, v.z, fmaf(v.w, v.w, q))));
            ushort4 h, lo;
            h.x = f2bf(v.x); lo.x = f2bf(v.x - bf2f(h.x));
            h.y = f2bf(v.y); lo.y = f2bf(v.y - bf2f(h.y));
            h.z = f2bf(v.z); lo.z = f2bf(v.z - bf2f(h.z));
            h.w = f2bf(v.w); lo.w = f2bf(v.w - bf2f(h.w));
            *(ushort4*)&Ah[row][part * 32 + j * 4] = h;
            *(ushort4*)&Al[row][part * 32 + j * 4] = lo;
        }
        q += __shfl_xor(q, 1, 64);
        q += __shfl_xor(q, 2, 64);
        if (part == 0) sx2[row] = q;
    }
    __syncthreads();

    // ---- X fragments -> registers (shared by all chunks) ----
    short8 xh[4][4], xl[4][4];     // [sample-tile n][kstep kk]
    #pragma unroll
    for (int n = 0; n < 4; ++n)
        #pragma unroll
        for (int kk = 0; kk < 4; ++kk) {
            int r2 = n * 16 + l15, c = kk * 32 + lk * 8;
            xh[n][kk] = *(const short8*)&Ah[r2][c];
            xl[n][kk] = *(const short8*)&Al[r2][c];
        }

    float m1[4], m2[4]; int ag[4];
    #pragma unroll
    for (int n = 0; n < 4; ++n) { m1[n] = 3.4e38f; m2[n] = 3.4e38f; ag[n] = 0; }

    for (int chunk = 0; chunk < 8; ++chunk) {
        int cb = chunk * 64 + wave * 16;   // this wave's 16-center slice
        const unsigned short* pch = Chi + (size_t)(cb + l15) * D + lk * 8;
        const unsigned short* pcl = Clo + (size_t)(cb + l15) * D + lk * 8;
        short8 ah[4], al[4];
        #pragma unroll
        for (int kk = 0; kk < 4; ++kk) {
            ah[kk] = *(const short8*)(pch + kk * 32);
            al[kk] = *(const short8*)(pcl + kk * 32);
        }
        f32x4 acc[4];
        #pragma unroll
        for (int n = 0; n < 4; ++n) acc[n] = (f32x4){0.f, 0.f, 0.f, 0.f};
        #pragma unroll
        for (int kk = 0; kk < 4; ++kk) {
            #pragma unroll
            for (int n = 0; n < 4; ++n)
                acc[n] = __builtin_amdgcn_mfma_f32_16x16x32_bf16(ah[kk], xh[n][kk], acc[n], 0, 0, 0);
            #pragma unroll
            for (int n = 0; n < 4; ++n)
                acc[n] = __builtin_amdgcn_mfma_f32_16x16x32_bf16(ah[kk], xl[n][kk], acc[n], 0, 0, 0);
            #pragma unroll
            for (int n = 0; n < 4; ++n)
                acc[n] = __builtin_amdgcn_mfma_f32_16x16x32_bf16(al[kk], xh[n][kk], acc[n], 0, 0, 0);
        }
        float cc[4];
        #pragma unroll
        for (int r = 0; r < 4; ++r) cc[r] = c2[cb + lk * 4 + r];
        #pragma unroll
        for (int n = 0; n < 4; ++n)
            #pragma unroll
            for (int r = 0; r < 4; ++r) {
                float s = fmaf(-2.f, acc[n][r], cc[r]);
                int ci = cb + lk * 4 + r;
                bool b = s < m1[n];
                m2[n] = b ? m1[n] : fminf(m2[n], s);
                m1[n] = b ? s : m1[n];
                ag[n] = b ? ci : ag[n];
            }
    }

    // ---- merge across lk groups (lanes ^16, ^32 share the same sample col) ----
    #pragma unroll
    for (int off = 16; off <= 32; off <<= 1)
        #pragma unroll
        for (int n = 0; n < 4; ++n) {
            float o1 = __shfl_xor(m1[n], off, 64);
            float o2 = __shfl_xor(m2[n], off, 64);
            int   oa = __shfl_xor(ag[n], off, 64);
            bool b = (o1 < m1[n]) || (o1 == m1[n] && oa < ag[n]);
            float lo1 = b ? o1 : m1[n];
            float hi1 = b ? m1[n] : o1;
            m2[n] = fminf(fminf(m2[n], o2), hi1);
            m1[n] = lo1;
            ag[n] = b ? oa : ag[n];
        }
    if (lane < 16) {
        #pragma unroll
        for (int n = 0; n < 4; ++n) {
            red1[wave][n * 16 + l15] = m1[n];
            red2[wave][n * 16 + l15] = m2[n];
            reda[wave][n * 16 + l15] = ag[n];
        }
    }
    __syncthreads();

    // ---- cross-wave merge + output ----
    if (tid < 64) {
        float M1 = red1[0][tid], M2 = red2[0][tid]; int A = reda[0][tid];
        #pragma unroll
        for (int w = 1; w < 4; ++w) {
            float o1 = red1[w][tid], o2 = red2[w][tid]; int oa = reda[w][tid];
            bool b = (o1 < M1) || (o1 == M1 && oa < A);
            float lo1 = b ? o1 : M1;
            float hi1 = b ? M1 : o1;
            M2 = fminf(fminf(M2, o2), hi1);
            M1 = lo1;
            A = b ? oa : A;
        }
        int i = s0 + tid;
        labF[i] = (float)A;
        labI[i] = A;
        mindist[i] = sx2[tid] + M1;
        if (M2 - M1 < TAU) {
            int p = atomicAdd(flagCount, 1);
            if (p < FLAG_CAP) flags[p] = i;
        }
    }
}

__global__ void k_refine(const float* __restrict__ X, const float* __restrict__ C,
                         const int* __restrict__ flagCount, const int* __restrict__ flags,
                         float* __restrict__ labF, float* __restrict__ mindist,
                         int* __restrict__ labI)
{
    int nf = *flagCount;
    if (nf > FLAG_CAP) nf = FLAG_CAP;
    int lane = threadIdx.x;  // block of 64 = 1 wave
    for (int f = blockIdx.x; f < nf; f += gridDim.x) {
        int i = flags[f];
        const float* xr = X + (size_t)i * D;
        double best = 1e300;
        int bestk = K;
        for (int k = lane; k < K; k += 64) {
            const float* ck = C + (size_t)k * D;
            double dot = 0.0, cc = 0.0;
            for (int d = 0; d < D; ++d) {
                double cd = (double)ck[d];
                dot = fma((double)xr[d], cd, dot);
                cc  = fma(cd, cd, cc);
            }
            double s = cc - 2.0 * dot;
            if (s < best) { best = s; bestk = k; }
        }
        #pragma unroll
        for (int off = 32; off > 0; off >>= 1) {
            double ob = __shfl_xor(best, off, 64);
            int okk   = __shfl_xor(bestk, off, 64);
            if (ob < best || (ob == best && okk < bestk)) { best = ob; bestk = okk; }
        }
        if (lane == 0) {
            double xx = 0.0;
            for (int d = 0; d < D; ++d) xx = fma((double)xr[d], (double)xr[d], xx);
            labF[i] = (float)bestk;
            labI[i] = bestk;
            mindist[i] = (float)(xx + best);
        }
    }
}

__global__ void k_loss(const float* __restrict__ mindist, double* __restrict__ lossSum) {
    __shared__ double sh[4];
    double s = 0.0;
    for (int i = blockIdx.x * blockDim.x + threadIdx.x; i < NS; i += gridDim.x * blockDim.x)
        s += (double)mindist[i];
    #pragma unroll
    for (int off = 32; off > 0; off >>= 1) s += __shfl_xor(s, off, 64);
    int wid = threadIdx.x >> 6, lane = threadIdx.x & 63;
    if (lane == 0) sh[wid] = s;
    __syncthreads();
    if (threadIdx.x == 0) {
        double t = (sh[0] + sh[1]) + (sh[2] + sh[3]);
        atomicAdd(lossSum, t);
    }
}

// Per-block histogram via LDS atomics (no global atomics).
__global__ __launch_bounds__(256) void k_bh(const int* __restrict__ labI,
                                            int* __restrict__ H) {
    __shared__ int h[K];
    for (int c = threadIdx.x; c < K; c += 256) h[c] = 0;
    __syncthreads();
    int base = blockIdx.x * ITEMS;
    #pragma unroll
    for (int it = 0; it < ITEMS / 256; ++it)
        atomicAdd(&h[labI[base + it * 256 + threadIdx.x]], 1);
    __syncthreads();
    for (int c = threadIdx.x; c < K; c += 256) H[blockIdx.x * K + c] = h[c];
}

// Column-scan H (per center over blocks) + block-wide prefix scan of totals.
// Afterwards H[b][c] = deterministic base cursor; counts[c] = bucket size.
__global__ void k_sc(int* __restrict__ H, int* __restrict__ counts) {
    __shared__ int sh[K];
    int c = threadIdx.x;
    int run = 0;
    for (int b = 0; b < NB; ++b) { int t = H[b * K + c]; H[b * K + c] = run; run += t; }
    counts[c] = run;
    sh[c] = run;
    __syncthreads();
    int my = run;
    for (int off = 1; off < K; off <<= 1) {
        int v = (c >= off) ? sh[c - off] : 0;
        __syncthreads();
        sh[c] += v;
        __syncthreads();
    }
    int excl = sh[c] - my;
    for (int b = 0; b < NB; ++b) H[b * K + c] += excl;
}

// Scatter with per-block LDS cursors — zero global atomics.
__global__ __launch_bounds__(256) void k_scatter2(const int* __restrict__ labI,
                                                  const int* __restrict__ H,
                                                  int* __restrict__ bucket) {
    __shared__ int cur[K];
    for (int c = threadIdx.x; c < K; c += 256) cur[c] = H[blockIdx.x * K + c];
    __syncthreads();
    int base = blockIdx.x * ITEMS;
    #pragma unroll
    for (int it = 0; it < ITEMS / 256; ++it) {
        int i = base + it * 256 + threadIdx.x;
        int pos = atomicAdd(&cur[labI[i]], 1);
        bucket[pos] = i;
    }
}

// Fixed segments of sorted bucket array; int64 fixed-point accumulation is
// order-independent -> bit-deterministic despite nondeterministic scatter order.
__global__ __launch_bounds__(128) void k_sumseg(
    const float* __restrict__ X, const int* __restrict__ labI,
    const int* __restrict__ bucket, unsigned long long* __restrict__ acc)
{
    int d = threadIdx.x;
    int beg = blockIdx.x * SEG;
    long long s = 0;
    int prev = -1;
    for (int j = beg; j < beg + SEG; ++j) {
        int idx = bucket[j];
        int lab = labI[idx];                 // uniform across the block
        if (lab != prev) {
            if (prev >= 0) atomicAdd(&acc[(size_t)prev * D + d], (unsigned long long)s);
            s = 0; prev = lab;
        }
        float v = X[(size_t)idx * D + d];
        s += (long long)__float2int_rn(v * FIXSCALE);
    }
    if (prev >= 0) atomicAdd(&acc[(size_t)prev * D + d], (unsigned long long)s);
}

__global__ void k_avg(const float* __restrict__ C, const int* __restrict__ cnt,
                      const int* __restrict__ counts,
                      const unsigned long long* __restrict__ acc,
                      float* __restrict__ outC, float* __restrict__ outCnt,
                      const double* __restrict__ lossSum, float* __restrict__ outLoss)
{
    int t = blockIdx.x * blockDim.x + threadIdx.x;   // over K*D
    int c = t >> 7, d = t & 127;
    double s = (double)(long long)acc[t] * INVFIX;
    int m = counts[c], n0 = cnt[c];
    double nm = (double)(n0 + m);
    outC[t] = (float)(((double)n0 * (double)C[t] + s) / nm);
    if (d == 0) outCnt[c] = (float)(n0 + m);
    if (t == 0) outLoss[0] = (float)(*lossSum / (double)NS);
}

extern "C" void kernel_launch(void* const* d_in, const int* in_sizes, int n_in,
                              void* d_out, int out_size, void* d_ws, size_t ws_size,
                              hipStream_t stream)
{
    const float* X  = (const float*)d_in[0];
    const float* C  = (const float*)d_in[1];
    const int* cnt  = (const int*)d_in[2];

    float* out     = (float*)d_out;
    float* outLoss = out;
    float* outLab  = out + 1;
    float* outCen  = out + 1 + NS;
    float* outCnt  = out + 1 + NS + (size_t)K * D;

    char* ws = (char*)d_ws;
    double* lossSum = (double*)(ws + 0);
    int* flagCount  = (int*)(ws + 8);
    float* c2       = (float*)(ws + 16);
    int* counts     = (int*)(ws + 2064);
    float* mindist  = (float*)(ws + 8208);
    int* labI       = (int*)(ws + 532496);
    int* flags      = (int*)(ws + 1056784);
    int* H          = (int*)(ws + 1187856);
    int* bucket     = (int*)(ws + 1318928);
    unsigned long long* acc = (unsigned long long*)(ws + 1843216);
    unsigned short* Chi = (unsigned short*)(ws + 2367504);
    unsigned short* Clo = (unsigned short*)(ws + 2498576);

    hipMemsetAsync(d_ws, 0, 16, stream);                        // lossSum, flagCount
    hipMemsetAsync(ws + 1843216, 0, (size_t)K * D * 8, stream); // acc
    k_prep<<<K / 4, 256, 0, stream>>>(C, c2, Chi, Clo);
    k_dist<<<NS / 64, 256, 0, stream>>>(X, Chi, Clo, c2, outLab, mindist, labI, flags, flagCount);
    k_refine<<<2048, 64, 0, stream>>>(X, C, flagCount, flags, outLab, mindist, labI);
    k_loss<<<256, 256, 0, stream>>>(mindist, lossSum);
    k_bh<<<NB, 256, 0, stream>>>(labI, H);
    k_sc<<<1, K, 0, stream>>>(H, counts);
    k_scatter2<<<NB, 256, 0, stream>>>(labI, H, bucket);
    k_sumseg<<<NS / SEG, 128, 0, stream>>>(X, labI, bucket, acc);
    k_avg<<<K * D / 256, 256, 0, stream>>>(C, cnt, counts, acc, outCen, outCnt, lossSum, outLoss);
}